// Round 8
// baseline (7509.333 us; speedup 1.0000x reference)
//
#include <hip/hip_runtime.h>

#define N_CLOUDS 16
#define PTS      16384
#define M        4096
#define THREADS  1024
#define NWAVES   16
#define PPT      16                 // consecutive points per thread

typedef float v2f __attribute__((ext_vector_type(2)));
typedef unsigned long long u64;
typedef unsigned int u32;

// One block per cloud; serial FPS. Round-8: single-barrier iteration.
//  R7 evidence: issue is near-floor (320 inst/wave/iter) but ~1400 cyc/iter
//  of stalls in the B1..B2 serial tail (LDS atomics + 2 barriers + 120-cyc
//  LDS hops). Fix:
//  - each wave resolves its OWN winner (coords+idx) pre-barrier in parallel:
//    readlane(wave-max) -> ballot -> first candidate lane scans its 8 pairs
//    -> plain LDS write {x,y,z,idxbits} + wave max. No atomics.
//  - ONE __syncthreads; then block winner via u64 (maxbits<<32 | ~wave) DPP
//    reduce over 16 wave entries + readlane + one broadcast LDS float4 read.
//  - parity double-buffered swv/scoord (write@i+2 vs read@i fenced by B1@i+1).
//  - state pinned in VGPRs INSIDE the loop (R4/R5/R7: out-of-loop pins let
//    the allocator park state in AGPRs; VGPR_Count 44-88. In-loop pin makes
//    VGPR residency the cheapest plan; launch_bounds(1024,4) caps at 128).
//  - tie-breaks exactly first-occurrence: smaller wave (~w key), smaller lane
//    (ffs), smaller slot (descending scan) — ownership is tid-consecutive.
//  - contract-off exact math (absmax=0 rounds 2-7).

#define PAIRS_X(X) X(0) X(1) X(2) X(3) X(4) X(5) X(6) X(7)
#define F12_X(X) X(0) X(1) X(2) X(3) X(4) X(5) X(6) X(7) X(8) X(9) X(10) X(11)
// QUAD(j0,j1,a,b,c): pairs j0=2m, j1=2m+1 from float4 f_a,f_b,f_c
// (points 4m..4m+3 = 12 floats: x0 y0 z0 x1 y1 z1 x2 y2 z2 x3 y3 z3)
#define QUADS_X(X) X(0,1,0,1,2) X(2,3,3,4,5) X(4,5,6,7,8) X(6,7,9,10,11)

// f32 max-combine with DPP-shifted copy (old=0 = +0.0f, identity: dists >= 0)
#define DPP_FMAX(bd, CTRL) { \
        const int t_ = __builtin_amdgcn_update_dpp(0, __float_as_int(bd), (CTRL), 0xf, 0xf, false); \
        (bd) = fmaxf((bd), __int_as_float(t_)); }
// u64 max-combine (old=0 identity: keys > 0)
#define DPP_KMAX(key, CTRL) { \
        const u32 lo_  = (u32)(key); \
        const u32 hi_  = (u32)((key) >> 32); \
        const u32 lo2_ = (u32)__builtin_amdgcn_update_dpp(0, (int)lo_, (CTRL), 0xf, 0xf, false); \
        const u32 hi2_ = (u32)__builtin_amdgcn_update_dpp(0, (int)hi_, (CTRL), 0xf, 0xf, false); \
        const u64 ok_  = ((u64)hi2_ << 32) | lo2_; \
        (key) = (ok_ > (key)) ? ok_ : (key); }

#define PIN8(a,b,c,d,e,g,h,k) asm volatile("" : "+v"(a),"+v"(b),"+v"(c),"+v"(d),"+v"(e),"+v"(g),"+v"(h),"+v"(k));

__global__ __launch_bounds__(THREADS, 4) void fps_kernel(
    const float* __restrict__ pos, int* __restrict__ out)
{
#pragma clang fp contract(off)
    __shared__ float  swv[2][NWAVES];     // per-wave max (parity-buffered)
    __shared__ float4 scoord[2][NWAVES];  // per-wave winner {x,y,z,idxbits}

    const int cloud = blockIdx.x;
    const int tid   = threadIdx.x;
    const int base  = cloud * PTS;

    // ---- query = point 0 of cloud ----
    const float q0x = pos[(size_t)base * 3 + 0];
    const float q0y = pos[(size_t)base * 3 + 1];
    const float q0z = pos[(size_t)base * 3 + 2];
    v2f qx2 = {q0x, q0x}, qy2 = {q0y, q0y}, qz2 = {q0z, q0z};

    // ---- one-time load: 16 consecutive pts = 12 float4/thread ----
    const float4* pos4 = (const float4*)pos;
    const int fo = cloud * (PTS * 3 / 4) + tid * (PPT * 3 / 4);
#define LOADF(n) const float4 f##n = pos4[fo + (n)];
    F12_X(LOADF)
#undef LOADF

    // ---- register state: 8 v2f per coord + 8 v2f dists = 64 floats ----
#define DECL(j) v2f XX##j, YY##j, ZZ##j, dd##j;
    PAIRS_X(DECL)
#undef DECL
#define REPACK(j0, j1, a, b, c) \
        XX##j0 = (v2f){f##a.x, f##a.w}; \
        YY##j0 = (v2f){f##a.y, f##b.x}; \
        ZZ##j0 = (v2f){f##a.z, f##b.y}; \
        XX##j1 = (v2f){f##b.z, f##c.y}; \
        YY##j1 = (v2f){f##b.w, f##c.z}; \
        ZZ##j1 = (v2f){f##c.x, f##c.w};
    QUADS_X(REPACK)
#undef REPACK

    // ---- init dists to point 0; value-only partial maxes ----
    float bd0 = -1.0f, bd1 = -1.0f;
#define INITP(j, BD) { \
        v2f dx = XX##j - qx2; \
        v2f dy = YY##j - qy2; \
        v2f dz = ZZ##j - qz2; \
        v2f nd = (dx * dx + dy * dy) + dz * dz; \
        dd##j = nd; \
        BD = fmaxf(fmaxf(nd.x, nd.y), BD); }
    INITP(0, bd0) INITP(1, bd0) INITP(2, bd0) INITP(3, bd0)
    INITP(4, bd1) INITP(5, bd1) INITP(6, bd1) INITP(7, bd1)
#undef INITP

    if (tid == 0) out[cloud * M] = base;   // first sample = point 0

    const int wave = tid >> 6;
    const int lane = tid & 63;

#pragma unroll 1
    for (int i = 1; i < M; ++i) {
        // ---- pin loop state into VGPRs every iteration ----
        PIN8(XX0, XX1, XX2, XX3, XX4, XX5, XX6, XX7)
        PIN8(YY0, YY1, YY2, YY3, YY4, YY5, YY6, YY7)
        PIN8(ZZ0, ZZ1, ZZ2, ZZ3, ZZ4, ZZ5, ZZ6, ZZ7)
        PIN8(dd0, dd1, dd2, dd3, dd4, dd5, dd6, dd7)

        const int p = i & 1;

        // ---- wave f32 max via DPP; broadcast to wave via readlane ----
        float bd = fmaxf(bd0, bd1);
        DPP_FMAX(bd, 0x111)   // row_shr:1
        DPP_FMAX(bd, 0x112)   // row_shr:2
        DPP_FMAX(bd, 0x114)   // row_shr:4
        DPP_FMAX(bd, 0x118)   // row_shr:8
        DPP_FMAX(bd, 0x142)   // row_bcast:15
        DPP_FMAX(bd, 0x143)   // row_bcast:31 -> lane 63 = wave max
        const float wm = __int_as_float(
            __builtin_amdgcn_readlane(__float_as_int(bd), 63));  // wave-uniform

        // ---- this wave's winner: first candidate lane scans its 8 pairs ----
        const bool c0 = (bd0 == wm);
        const bool c1 = (bd1 == wm);
        const u64 bal = __ballot(c0 || c1);
        if ((c0 || c1) && lane == (__ffsll(bal) - 1)) {
            int k = 0; float xs = 0.0f, ys = 0.0f, zs = 0.0f;
#define SCANJ(j) { if (dd##j.y == wm) { k = 2*(j)+1; xs = XX##j.y; ys = YY##j.y; zs = ZZ##j.y; } \
                   if (dd##j.x == wm) { k = 2*(j);   xs = XX##j.x; ys = YY##j.x; zs = ZZ##j.x; } }
            if (c0) { SCANJ(3) SCANJ(2) SCANJ(1) SCANJ(0) }
            else    { SCANJ(7) SCANJ(6) SCANJ(5) SCANJ(4) }
#undef SCANJ
            swv[p][wave]    = wm;
            scoord[p][wave] = make_float4(xs, ys, zs,
                                          __int_as_float(tid * PPT + k));
        }
        __syncthreads();   // the ONLY barrier

        // ---- block winner: u64 (maxbits<<32 | ~wave) over 16 entries ----
        const int w = lane & 15;
        u64 key = ((u64)__float_as_uint(swv[p][w]) << 32) | (u32)(~w);
        DPP_KMAX(key, 0x111)
        DPP_KMAX(key, 0x112)
        DPP_KMAX(key, 0x114)
        DPP_KMAX(key, 0x118)   // lane 15 of each row = max of 16
        const u32 lo = __builtin_amdgcn_readlane((u32)key, 15);
        const int ww = (int)(~lo) & 15;               // winning wave (uniform)

        const float4 wc = scoord[p][ww];              // broadcast LDS read
        if (tid == 0) out[cloud * M + i] = base + __float_as_int(wc.w);
        qx2 = (v2f){wc.x, wc.x};
        qy2 = (v2f){wc.y, wc.y};
        qz2 = (v2f){wc.z, wc.z};

        // ---- distance update + value-only partial maxes ----
        bd0 = -1.0f; bd1 = -1.0f;
#define UPD(j, BD) { \
        v2f dx = XX##j - qx2; \
        v2f dy = YY##j - qy2; \
        v2f dz = ZZ##j - qz2; \
        v2f nd = (dx * dx + dy * dy) + dz * dz; \
        dd##j.x = fminf(dd##j.x, nd.x); \
        dd##j.y = fminf(dd##j.y, nd.y); \
        BD = fmaxf(fmaxf(dd##j.x, dd##j.y), BD); }
        UPD(0, bd0) UPD(1, bd0) UPD(2, bd0) UPD(3, bd0)
        UPD(4, bd1) UPD(5, bd1) UPD(6, bd1) UPD(7, bd1)
#undef UPD
    }
}

extern "C" void kernel_launch(void* const* d_in, const int* in_sizes, int n_in,
                              void* d_out, int out_size, void* d_ws, size_t ws_size,
                              hipStream_t stream) {
    const float* pos = (const float*)d_in[0];
    int* out = (int*)d_out;
    fps_kernel<<<N_CLOUDS, THREADS, 0, stream>>>(pos, out);
}